// Round 3
// baseline (359.265 us; speedup 1.0000x reference)
//
#include <hip/hip_runtime.h>

constexpr int BOND = 64;
constexpr int RANK = 16;
constexpr int BT   = 8;    // batch tile per block
constexpr int NTHR = 256;
constexpr int LPAD = 68;   // leaf row stride (floats): 272 B, 16B-aligned

typedef short  short8 __attribute__((ext_vector_type(8)));  // 8 bf16 (4 VGPRs)
typedef float  f32x4  __attribute__((ext_vector_type(4)));

// factor row offsets per level: L0:0  L1:1  L2:5  L3:21  L4:85  L5:341

__device__ __forceinline__ unsigned short f2bf(float f) {
    union { float f; unsigned u; } v; v.f = f;
    unsigned r = v.u + 0x7FFFu + ((v.u >> 16) & 1u);   // RNE
    return (unsigned short)(r >> 16);
}

__device__ __forceinline__ void node_lat(const float* __restrict__ f_in,
                                         const float* __restrict__ scale,
                                         int fo,
                                         const float* xin,   // LDS [BT][64]
                                         float* lat,         // LDS [BT][16]
                                         int tid)
{
    const int b = tid >> 5;
    const int r = (tid >> 1) & 15;
    const int h = tid & 1;
    const float4* fir = (const float4*)(f_in + (size_t)fo * (RANK * BOND) + r * BOND + h * 32);
    const float4* xb  = (const float4*)(xin + b * BOND + h * 32);
    float p = 0.f;
#pragma unroll
    for (int i = 0; i < 8; ++i) {
        const float4 a = fir[i], c = xb[i];
        p += a.x * c.x + a.y * c.y + a.z * c.z + a.w * c.w;
    }
    p += __shfl_xor(p, 1);
    if (h == 0) lat[b * RANK + r] = p * scale[fo * RANK + r];
}

__device__ __forceinline__ void node_children(const float* __restrict__ fd, // global [16][64] at node
                                              const float* xin,   // LDS [BT][64]
                                              const float* lat,   // LDS [BT][16]
                                              float* xout,        // LDS, row b at xout[b*bstride]
                                              int bstride,
                                              int tid)
{
    const int o  = tid & 63;
    const int b0 = tid >> 6;
    float f[RANK];
#pragma unroll
    for (int r = 0; r < RANK; ++r) f[r] = fd[r * BOND + o];
#pragma unroll
    for (int bi = 0; bi < BT; bi += 4) {
        const int b = b0 + bi;
        float acc = xin[b * BOND + o];
#pragma unroll
        for (int r = 0; r < RANK; ++r) acc += lat[b * RANK + r] * f[r];
        xout[b * bstride + o] = acc;
    }
}

__global__ __launch_bounds__(NTHR, 4)
void qtree_kernel(const float* __restrict__ x,      // [128][1][64]
                  const float* __restrict__ f_in,   // [1365][16][64]
                  const float* __restrict__ f_tl,
                  const float* __restrict__ f_tr,
                  const float* __restrict__ f_bl,
                  const float* __restrict__ f_br,
                  const float* __restrict__ scale,  // [1365][16]
                  const float* __restrict__ head_w, // [48][64]
                  const float* __restrict__ head_b, // [48]
                  float* __restrict__ out)          // [128][3][256][256]
{
    __shared__ float s_x4[2][BT][BOND];       // 4 KB
    __shared__ float s_x5[4][BT][BOND];       // 8 KB
    __shared__ float s_leafy[64 * LPAD];      // 17 KB: leaves, aliased as s_y[8][3][8][16]
    __shared__ float s_lat[4][BT][RANK];      // 2 KB
    // total ~31 KB -> LDS allows 5 blocks/CU

    const int tid  = threadIdx.x;
    const int lane = tid & 63;
    const int wv   = tid >> 6;     // wave id 0..3 -> N-tile (16 leaves)
    const int m    = lane & 15;    // M/N row within tile
    const int q    = lane >> 4;    // quad
    const int n3   = blockIdx.x;   // 0..63  level-3 node (y3*8+x3)
    const int bg   = blockIdx.y;   // 0..15  batch group
    const int jy   = blockIdx.z;   // 0..1
    const int y3   = n3 >> 3, x3 = n3 & 7;

    const float* fdir[4] = { f_tl, f_tr, f_bl, f_br };

    // ---- per-lane head state (registers, reused by all 4 head passes) ----
    // A-fragments: head_w rows (M = output o), bf16.  A[m][k]: k = kc*32 + q*8 + j
    short8 afrag[3][2];
#pragma unroll
    for (int mt = 0; mt < 3; ++mt)
#pragma unroll
        for (int kc = 0; kc < 2; ++kc) {
            const float* src = head_w + (mt * 16 + m) * 64 + kc * 32 + q * 8;
            short8 a;
#pragma unroll
            for (int j = 0; j < 8; ++j) a[j] = (short)f2bf(src[j]);
            afrag[mt][kc] = a;
        }
    // bias -> MFMA C init:  o = mt*16 + q*4 + r
    f32x4 accinit[3];
#pragma unroll
    for (int mt = 0; mt < 3; ++mt)
#pragma unroll
        for (int r = 0; r < 4; ++r) accinit[mt][r] = head_b[mt * 16 + q * 4 + r];
    // staging offsets: leaf = wv*16 + m -> (b, dx2, c)
    const int leaf = wv * 16 + m;
    const int lb = leaf >> 3, ldx = (leaf >> 2) & 1, lc = leaf & 3;
    const int lcy = lc >> 1, lcx = lc & 1;
    const int sy_base = lb * 384 + lcy * 64 + ldx * 8 + lcx * 4;
    int sy_ofs[3][4];
#pragma unroll
    for (int mt = 0; mt < 3; ++mt)
#pragma unroll
        for (int r = 0; r < 4; ++r) {
            const int o = mt * 16 + q * 4 + r;
            sy_ofs[mt][r] = sy_base + (o % 3) * 128 + (o / 12) * 16 + ((o / 3) & 3);
        }

    // load x for this batch group into s_x5[0]
    for (int i4 = tid; i4 < BT * BOND / 4; i4 += NTHR)
        ((float4*)&s_x5[0][0][0])[i4] = ((const float4*)(x + (size_t)bg * BT * BOND))[i4];
    __syncthreads();

    // ---- ancestor path L0 -> L1 -> L2 ----
    {
        node_lat(f_in, scale, 0, &s_x5[0][0][0], &s_lat[0][0][0], tid);
        __syncthreads();
        const int d = ((y3 >> 2) << 1) | (x3 >> 2);
        node_children(fdir[d], &s_x5[0][0][0], &s_lat[0][0][0], &s_x5[1][0][0], BOND, tid);
        __syncthreads();
    }
    {
        const int fo = 1 + ((y3 >> 2) * 2 + (x3 >> 2));
        node_lat(f_in, scale, fo, &s_x5[1][0][0], &s_lat[0][0][0], tid);
        __syncthreads();
        const int d = (((y3 >> 1) & 1) << 1) | ((x3 >> 1) & 1);
        node_children(fdir[d] + (size_t)fo * RANK * BOND, &s_x5[1][0][0], &s_lat[0][0][0], &s_x5[2][0][0], BOND, tid);
        __syncthreads();
    }
    {
        const int fo = 5 + ((y3 >> 1) * 4 + (x3 >> 1));
        node_lat(f_in, scale, fo, &s_x5[2][0][0], &s_lat[0][0][0], tid);
        __syncthreads();
        const int d = ((y3 & 1) << 1) | (x3 & 1);
        node_children(fdir[d] + (size_t)fo * RANK * BOND, &s_x5[2][0][0], &s_lat[0][0][0], &s_x5[3][0][0], BOND, tid);
        __syncthreads();
    }
    // ---- L3: children for d = 2*jy + jx -> s_x4[jx] ----
    {
        const int fo = 21 + n3;
        node_lat(f_in, scale, fo, &s_x5[3][0][0], &s_lat[0][0][0], tid);
        __syncthreads();
#pragma unroll
        for (int jx = 0; jx < 2; ++jx)
            node_children(fdir[2 * jy + jx] + (size_t)fo * RANK * BOND,
                          &s_x5[3][0][0], &s_lat[0][0][0], &s_x4[jx][0][0], BOND, tid);
        __syncthreads();
    }

    // ---- two L4 subtrees, depth-first ----
    for (int jx = 0; jx < 2; ++jx) {
        const int y4 = 2 * y3 + jy, x4c = 2 * x3 + jx;
        const int fo4 = 85 + y4 * 16 + x4c;
        node_lat(f_in, scale, fo4, &s_x4[jx][0][0], &s_lat[0][0][0], tid);
        __syncthreads();
#pragma unroll
        for (int e = 0; e < 4; ++e)
            node_children(fdir[e] + (size_t)fo4 * RANK * BOND,
                          &s_x4[jx][0][0], &s_lat[0][0][0], &s_x5[e][0][0], BOND, tid);
        __syncthreads();

        int fo5[4];
#pragma unroll
        for (int e = 0; e < 4; ++e) {
            const int dy = e >> 1, dx = e & 1;
            fo5[e] = 341 + (2 * y4 + dy) * 32 + (2 * x4c + dx);
            node_lat(f_in, scale, fo5[e], &s_x5[e][0][0], &s_lat[e][0][0], tid);
        }
        __syncthreads();

        for (int p = 0; p < 2; ++p) {
            // children for e = 2p+dx2 -> leaf rows (b*8 + dx2*4 + c)
#pragma unroll
            for (int dx2 = 0; dx2 < 2; ++dx2) {
                const int e = 2 * p + dx2;
#pragma unroll
                for (int c = 0; c < 4; ++c)
                    node_children(fdir[c] + (size_t)fo5[e] * RANK * BOND,
                                  &s_x5[e][0][0], &s_lat[e][0][0],
                                  s_leafy + (dx2 * 4 + c) * LPAD, 8 * LPAD, tid);
            }
            __syncthreads();

            // ---- MFMA head: D[o][leaf] = head_w x leaves^T + bias ----
            short8 bfrag[2];
#pragma unroll
            for (int kc = 0; kc < 2; ++kc) {
                const float* src = &s_leafy[leaf * LPAD + kc * 32 + q * 8];
                const float4 lo = *(const float4*)src;
                const float4 hi = *(const float4*)(src + 4);
                short8 bq;
                bq[0] = (short)f2bf(lo.x); bq[1] = (short)f2bf(lo.y);
                bq[2] = (short)f2bf(lo.z); bq[3] = (short)f2bf(lo.w);
                bq[4] = (short)f2bf(hi.x); bq[5] = (short)f2bf(hi.y);
                bq[6] = (short)f2bf(hi.z); bq[7] = (short)f2bf(hi.w);
                bfrag[kc] = bq;
            }
            f32x4 acc[3];
#pragma unroll
            for (int mt = 0; mt < 3; ++mt) acc[mt] = accinit[mt];
#pragma unroll
            for (int kc = 0; kc < 2; ++kc)
#pragma unroll
                for (int mt = 0; mt < 3; ++mt)
                    acc[mt] = __builtin_amdgcn_mfma_f32_16x16x32_bf16(afrag[mt][kc], bfrag[kc], acc[mt], 0, 0, 0);
            __syncthreads();   // all waves done reading s_leafy

            // stage y (alias s_leafy): [b][ch][r2][c2] = [8][3][8][16]
            float* s_y = s_leafy;
#pragma unroll
            for (int mt = 0; mt < 3; ++mt)
#pragma unroll
                for (int r = 0; r < 4; ++r) s_y[sy_ofs[mt][r]] = acc[mt][r];
            __syncthreads();

            // coalesced 64B-aligned stores
            const int base_row = (4 * y3 + 2 * jy + p) * 8;
            const int base_col = (4 * x3 + 2 * jx) * 8;
#pragma unroll
            for (int s = 0; s < 3; ++s) {
                const int idx = tid + NTHR * s;    // 0..767 float4 chunks
                const int c4  = idx & 3;
                const int r2  = (idx >> 2) & 7;
                const int bc  = idx >> 5;          // b*3+ch
                const float4 v = *(const float4*)&s_y[(bc * 8 + r2) * 16 + c4 * 4];
                const size_t off = ((size_t)(bg * BT + bc / 3) * 3 + (bc % 3)) * 65536
                                 + (size_t)(base_row + r2) * 256 + base_col + c4 * 4;
                *(float4*)&out[off] = v;
            }
            __syncthreads();
        } // p
    } // jx
}

extern "C" void kernel_launch(void* const* d_in, const int* in_sizes, int n_in,
                              void* d_out, int out_size, void* d_ws, size_t ws_size,
                              hipStream_t stream) {
    const float* x    = (const float*)d_in[0];
    const float* f_in = (const float*)d_in[1];
    const float* f_tl = (const float*)d_in[2];
    const float* f_tr = (const float*)d_in[3];
    const float* f_bl = (const float*)d_in[4];
    const float* f_br = (const float*)d_in[5];
    const float* sc   = (const float*)d_in[6];
    const float* hw   = (const float*)d_in[7];
    const float* hb   = (const float*)d_in[8];
    float* out = (float*)d_out;

    dim3 grid(64, 16, 2);
    qtree_kernel<<<grid, NTHR, 0, stream>>>(x, f_in, f_tl, f_tr, f_bl, f_br, sc, hw, hb, out);
}

// Round 4
// 319.581 us; speedup vs baseline: 1.1242x; 1.1242x over previous
//
#include <hip/hip_runtime.h>

constexpr int BOND = 64;
constexpr int RANK = 16;
constexpr int BT   = 8;    // batch tile per block
constexpr int NTHR = 256;
constexpr int LPAD = 68;   // leaf row stride (floats): 272 B, 16B-aligned

typedef short  short8 __attribute__((ext_vector_type(8)));  // 8 bf16 (4 VGPRs)
typedef float  f32x4  __attribute__((ext_vector_type(4)));

// factor row offsets per level: L0:0  L1:1  L2:5  L3:21  L4:85  L5:341

__device__ __forceinline__ unsigned short f2bf(float f) {
    union { float f; unsigned u; } v; v.f = f;
    unsigned r = v.u + 0x7FFFu + ((v.u >> 16) & 1u);   // RNE
    return (unsigned short)(r >> 16);
}

__device__ __forceinline__ void node_lat(const float* __restrict__ f_in,
                                         const float* __restrict__ scale,
                                         int fo,
                                         const float* xin,   // LDS [BT][64]
                                         float* lat,         // LDS [BT][16]
                                         int tid)
{
    const int b = tid >> 5;
    const int r = (tid >> 1) & 15;
    const int h = tid & 1;
    const float4* fir = (const float4*)(f_in + (size_t)fo * (RANK * BOND) + r * BOND + h * 32);
    const float4* xb  = (const float4*)(xin + b * BOND + h * 32);
    float p = 0.f;
#pragma unroll
    for (int i = 0; i < 8; ++i) {
        const float4 a = fir[i], c = xb[i];
        p += a.x * c.x + a.y * c.y + a.z * c.z + a.w * c.w;
    }
    p += __shfl_xor(p, 1);
    if (h == 0) lat[b * RANK + r] = p * scale[fo * RANK + r];
}

__device__ __forceinline__ void node_children(const float* __restrict__ fd, // global [16][64] at node
                                              const float* xin,   // LDS [BT][64]
                                              const float* lat,   // LDS [BT][16]
                                              float* xout,        // LDS, row b at xout[b*bstride]
                                              int bstride,
                                              int tid)
{
    const int o  = tid & 63;
    const int b0 = tid >> 6;
    float f[RANK];
#pragma unroll
    for (int r = 0; r < RANK; ++r) f[r] = fd[r * BOND + o];
#pragma unroll
    for (int bi = 0; bi < BT; bi += 4) {
        const int b = b0 + bi;
        float acc = xin[b * BOND + o];
#pragma unroll
        for (int r = 0; r < RANK; ++r) acc += lat[b * RANK + r] * f[r];
        xout[b * bstride + o] = acc;
    }
}

// min-waves/EU = 3 -> VGPR cap ~168. At 4 waves/EU the cap is 64 and the
// head's persistent register state (afrag+accinit+sy_ofs ~48 VGPR) spilled
// to scratch: R3 showed +136 MB FETCH / +125 MB WRITE of pure spill traffic.
__global__ __launch_bounds__(NTHR, 3)
void qtree_kernel(const float* __restrict__ x,      // [128][1][64]
                  const float* __restrict__ f_in,   // [1365][16][64]
                  const float* __restrict__ f_tl,
                  const float* __restrict__ f_tr,
                  const float* __restrict__ f_bl,
                  const float* __restrict__ f_br,
                  const float* __restrict__ scale,  // [1365][16]
                  const float* __restrict__ head_w, // [48][64]
                  const float* __restrict__ head_b, // [48]
                  float* __restrict__ out)          // [128][3][256][256]
{
    __shared__ float s_x4[2][BT][BOND];       // 4 KB
    __shared__ float s_x5[4][BT][BOND];       // 8 KB
    __shared__ float s_leafy[64 * LPAD];      // 17 KB: leaves, aliased as s_y[8][3][8][16]
    __shared__ float s_lat[4][BT][RANK];      // 2 KB
    // total ~31 KB

    const int tid  = threadIdx.x;
    const int lane = tid & 63;
    const int wv   = tid >> 6;     // wave id 0..3 -> N-tile (16 leaves)
    const int m    = lane & 15;    // M/N row within tile
    const int q    = lane >> 4;    // quad
    const int n3   = blockIdx.x;   // 0..63  level-3 node (y3*8+x3)
    const int bg   = blockIdx.y;   // 0..15  batch group
    const int jy   = blockIdx.z;   // 0..1
    const int y3   = n3 >> 3, x3 = n3 & 7;

    const float* fdir[4] = { f_tl, f_tr, f_bl, f_br };

    // ---- per-lane head state (registers, reused by all 4 head passes) ----
    // A-fragments: head_w rows (M = output o), bf16.  A[m][k]: k = kc*32 + q*8 + j
    short8 afrag[3][2];
#pragma unroll
    for (int mt = 0; mt < 3; ++mt)
#pragma unroll
        for (int kc = 0; kc < 2; ++kc) {
            const float* src = head_w + (mt * 16 + m) * 64 + kc * 32 + q * 8;
            short8 a;
#pragma unroll
            for (int j = 0; j < 8; ++j) a[j] = (short)f2bf(src[j]);
            afrag[mt][kc] = a;
        }
    // bias -> MFMA C init:  o = mt*16 + q*4 + r
    f32x4 accinit[3];
#pragma unroll
    for (int mt = 0; mt < 3; ++mt)
#pragma unroll
        for (int r = 0; r < 4; ++r) accinit[mt][r] = head_b[mt * 16 + q * 4 + r];
    // staging offsets: leaf = wv*16 + m -> (b, dx2, c)
    const int leaf = wv * 16 + m;
    const int lb = leaf >> 3, ldx = (leaf >> 2) & 1, lc = leaf & 3;
    const int lcy = lc >> 1, lcx = lc & 1;
    const int sy_base = lb * 384 + lcy * 64 + ldx * 8 + lcx * 4;
    int sy_ofs[3][4];
#pragma unroll
    for (int mt = 0; mt < 3; ++mt)
#pragma unroll
        for (int r = 0; r < 4; ++r) {
            const int o = mt * 16 + q * 4 + r;
            sy_ofs[mt][r] = sy_base + (o % 3) * 128 + (o / 12) * 16 + ((o / 3) & 3);
        }

    // load x for this batch group into s_x5[0]
    for (int i4 = tid; i4 < BT * BOND / 4; i4 += NTHR)
        ((float4*)&s_x5[0][0][0])[i4] = ((const float4*)(x + (size_t)bg * BT * BOND))[i4];
    __syncthreads();

    // ---- ancestor path L0 -> L1 -> L2 ----
    {
        node_lat(f_in, scale, 0, &s_x5[0][0][0], &s_lat[0][0][0], tid);
        __syncthreads();
        const int d = ((y3 >> 2) << 1) | (x3 >> 2);
        node_children(fdir[d], &s_x5[0][0][0], &s_lat[0][0][0], &s_x5[1][0][0], BOND, tid);
        __syncthreads();
    }
    {
        const int fo = 1 + ((y3 >> 2) * 2 + (x3 >> 2));
        node_lat(f_in, scale, fo, &s_x5[1][0][0], &s_lat[0][0][0], tid);
        __syncthreads();
        const int d = (((y3 >> 1) & 1) << 1) | ((x3 >> 1) & 1);
        node_children(fdir[d] + (size_t)fo * RANK * BOND, &s_x5[1][0][0], &s_lat[0][0][0], &s_x5[2][0][0], BOND, tid);
        __syncthreads();
    }
    {
        const int fo = 5 + ((y3 >> 1) * 4 + (x3 >> 1));
        node_lat(f_in, scale, fo, &s_x5[2][0][0], &s_lat[0][0][0], tid);
        __syncthreads();
        const int d = ((y3 & 1) << 1) | (x3 & 1);
        node_children(fdir[d] + (size_t)fo * RANK * BOND, &s_x5[2][0][0], &s_lat[0][0][0], &s_x5[3][0][0], BOND, tid);
        __syncthreads();
    }
    // ---- L3: children for d = 2*jy + jx -> s_x4[jx] ----
    {
        const int fo = 21 + n3;
        node_lat(f_in, scale, fo, &s_x5[3][0][0], &s_lat[0][0][0], tid);
        __syncthreads();
#pragma unroll
        for (int jx = 0; jx < 2; ++jx)
            node_children(fdir[2 * jy + jx] + (size_t)fo * RANK * BOND,
                          &s_x5[3][0][0], &s_lat[0][0][0], &s_x4[jx][0][0], BOND, tid);
        __syncthreads();
    }

    // ---- two L4 subtrees, depth-first ----
    for (int jx = 0; jx < 2; ++jx) {
        const int y4 = 2 * y3 + jy, x4c = 2 * x3 + jx;
        const int fo4 = 85 + y4 * 16 + x4c;
        node_lat(f_in, scale, fo4, &s_x4[jx][0][0], &s_lat[0][0][0], tid);
        __syncthreads();
#pragma unroll
        for (int e = 0; e < 4; ++e)
            node_children(fdir[e] + (size_t)fo4 * RANK * BOND,
                          &s_x4[jx][0][0], &s_lat[0][0][0], &s_x5[e][0][0], BOND, tid);
        __syncthreads();

        int fo5[4];
#pragma unroll
        for (int e = 0; e < 4; ++e) {
            const int dy = e >> 1, dx = e & 1;
            fo5[e] = 341 + (2 * y4 + dy) * 32 + (2 * x4c + dx);
            node_lat(f_in, scale, fo5[e], &s_x5[e][0][0], &s_lat[e][0][0], tid);
        }
        __syncthreads();

        for (int p = 0; p < 2; ++p) {
            // children for e = 2p+dx2 -> leaf rows (b*8 + dx2*4 + c)
#pragma unroll
            for (int dx2 = 0; dx2 < 2; ++dx2) {
                const int e = 2 * p + dx2;
#pragma unroll
                for (int c = 0; c < 4; ++c)
                    node_children(fdir[c] + (size_t)fo5[e] * RANK * BOND,
                                  &s_x5[e][0][0], &s_lat[e][0][0],
                                  s_leafy + (dx2 * 4 + c) * LPAD, 8 * LPAD, tid);
            }
            __syncthreads();

            // ---- MFMA head: D[o][leaf] = head_w x leaves^T + bias ----
            short8 bfrag[2];
#pragma unroll
            for (int kc = 0; kc < 2; ++kc) {
                const float* src = &s_leafy[leaf * LPAD + kc * 32 + q * 8];
                const float4 lo = *(const float4*)src;
                const float4 hi = *(const float4*)(src + 4);
                short8 bq;
                bq[0] = (short)f2bf(lo.x); bq[1] = (short)f2bf(lo.y);
                bq[2] = (short)f2bf(lo.z); bq[3] = (short)f2bf(lo.w);
                bq[4] = (short)f2bf(hi.x); bq[5] = (short)f2bf(hi.y);
                bq[6] = (short)f2bf(hi.z); bq[7] = (short)f2bf(hi.w);
                bfrag[kc] = bq;
            }
            f32x4 acc[3];
#pragma unroll
            for (int mt = 0; mt < 3; ++mt) acc[mt] = accinit[mt];
#pragma unroll
            for (int kc = 0; kc < 2; ++kc)
#pragma unroll
                for (int mt = 0; mt < 3; ++mt)
                    acc[mt] = __builtin_amdgcn_mfma_f32_16x16x32_bf16(afrag[mt][kc], bfrag[kc], acc[mt], 0, 0, 0);
            __syncthreads();   // all waves done reading s_leafy

            // stage y (alias s_leafy): [b][ch][r2][c2] = [8][3][8][16]
            float* s_y = s_leafy;
#pragma unroll
            for (int mt = 0; mt < 3; ++mt)
#pragma unroll
                for (int r = 0; r < 4; ++r) s_y[sy_ofs[mt][r]] = acc[mt][r];
            __syncthreads();

            // coalesced 64B-aligned stores
            const int base_row = (4 * y3 + 2 * jy + p) * 8;
            const int base_col = (4 * x3 + 2 * jx) * 8;
#pragma unroll
            for (int s = 0; s < 3; ++s) {
                const int idx = tid + NTHR * s;    // 0..767 float4 chunks
                const int c4  = idx & 3;
                const int r2  = (idx >> 2) & 7;
                const int bc  = idx >> 5;          // b*3+ch
                const float4 v = *(const float4*)&s_y[(bc * 8 + r2) * 16 + c4 * 4];
                const size_t off = ((size_t)(bg * BT + bc / 3) * 3 + (bc % 3)) * 65536
                                 + (size_t)(base_row + r2) * 256 + base_col + c4 * 4;
                *(float4*)&out[off] = v;
            }
            __syncthreads();
        } // p
    } // jx
}

extern "C" void kernel_launch(void* const* d_in, const int* in_sizes, int n_in,
                              void* d_out, int out_size, void* d_ws, size_t ws_size,
                              hipStream_t stream) {
    const float* x    = (const float*)d_in[0];
    const float* f_in = (const float*)d_in[1];
    const float* f_tl = (const float*)d_in[2];
    const float* f_tr = (const float*)d_in[3];
    const float* f_bl = (const float*)d_in[4];
    const float* f_br = (const float*)d_in[5];
    const float* sc   = (const float*)d_in[6];
    const float* hw   = (const float*)d_in[7];
    const float* hb   = (const float*)d_in[8];
    float* out = (float*)d_out;

    dim3 grid(64, 16, 2);
    qtree_kernel<<<grid, NTHR, 0, stream>>>(x, f_in, f_tl, f_tr, f_bl, f_br, sc, hw, hb, out);
}

// Round 6
// 317.024 us; speedup vs baseline: 1.1332x; 1.0081x over previous
//
#include <hip/hip_runtime.h>

constexpr int NTHR = 256;

typedef short  short8 __attribute__((ext_vector_type(8)));  // 8 bf16 (4 VGPRs)
typedef float  f32x4  __attribute__((ext_vector_type(4)));

// factor row offsets per level: L0:0  L1:1  L2:5  L3:21  L4:85  L5:341
// Zero-barrier design: each wave owns 2 batches and the whole tree for them.
// All LDS buffers are wave-private; intra-wave LDS ordering is guaranteed by
// compiler-inserted lgkmcnt waits (may-alias, same wave). No __syncthreads.

__device__ __forceinline__ unsigned short f2bf(float f) {
    union { float f; unsigned u; } v; v.f = f;
    unsigned r = v.u + 0x7FFFu + ((v.u >> 16) & 1u);   // RNE
    return (unsigned short)(r >> 16);
}

// lat[b][r] = scale[fo][r] * dot64(f_in[fo][r], xin[b])   (b=0..1, r=0..15)
__device__ __forceinline__ void wlat(const float* __restrict__ f_in,
                                     const float* __restrict__ scale,
                                     int fo,
                                     const float (*xin)[64],   // wave-private LDS [2][64]
                                     float (*lat)[16],         // wave-private LDS [2][16]
                                     int lane)
{
    const int b = lane >> 5;          // 0..1
    const int r = (lane >> 1) & 15;   // 0..15
    const int h = lane & 1;           // half of dot
    const float4* fir = (const float4*)(f_in + (size_t)fo * 1024 + r * 64 + h * 32);
    const float4* xb  = (const float4*)(&xin[b][0] + h * 32);
    float p = 0.f;
#pragma unroll
    for (int i = 0; i < 8; ++i) {
        const float4 a = fir[i], c = xb[i];
        p += a.x * c.x + a.y * c.y + a.z * c.z + a.w * c.w;
    }
    p += __shfl_xor(p, 1);
    if (h == 0) lat[b][r] = p * scale[fo * 16 + r];
}

// xout[b][o] = xin[b][o] + sum_r lat[b][r] * fd[r][o]
__device__ __forceinline__ void wchild(const float* __restrict__ fd,
                                       const float (*xin)[64],
                                       const float (*lat)[16],
                                       float (*xout)[64],
                                       int lane)
{
    const int o = lane;
    float f[16];
#pragma unroll
    for (int r = 0; r < 16; ++r) f[r] = fd[r * 64 + o];
#pragma unroll
    for (int b = 0; b < 2; ++b) {
        float acc = xin[b][o];
#pragma unroll
        for (int r = 0; r < 16; ++r) acc += lat[b][r] * f[r];
        xout[b][o] = acc;
    }
}

// leaf rows n = b*8 + nbase (bf16, stride 72 shorts)
__device__ __forceinline__ void wchild_leaf(const float* __restrict__ fd,
                                            const float (*xin)[64],
                                            const float (*lat)[16],
                                            unsigned short* leaf,   // [16][72]
                                            int nbase,
                                            int lane)
{
    const int o = lane;
    float f[16];
#pragma unroll
    for (int r = 0; r < 16; ++r) f[r] = fd[r * 64 + o];
#pragma unroll
    for (int b = 0; b < 2; ++b) {
        float acc = xin[b][o];
#pragma unroll
        for (int r = 0; r < 16; ++r) acc += lat[b][r] * f[r];
        leaf[(b * 8 + nbase) * 72 + o] = f2bf(acc);
    }
}

// min-waves/EU = 3 -> VGPR cap 168 (R3: cap 64 spilled; R4: 84 used, clean)
__global__ __launch_bounds__(NTHR, 3)
void qtree_kernel(const float* __restrict__ x,      // [128][64]
                  const float* __restrict__ f_in,   // [1365][16][64]
                  const float* __restrict__ f_tl,
                  const float* __restrict__ f_tr,
                  const float* __restrict__ f_bl,
                  const float* __restrict__ f_br,
                  const float* __restrict__ scale,  // [1365][16]
                  const float* __restrict__ head_w, // [48][64]
                  const float* __restrict__ head_b, // [48]
                  float* __restrict__ out)          // [128][3][256][256]
{
    __shared__ float s_xa[4][2][64];                // 2 KB  path ping
    __shared__ float s_xb[4][2][64];                // 2 KB  path pong
    __shared__ float s_x4[4][2][2][64];             // 4 KB  L3 children (jx)
    __shared__ float s_x5[4][4][2][64];             // 8 KB  L4 children (e)
    __shared__ float s_lat[4][2][16];               // 0.5 KB
    __shared__ unsigned short s_leaf[4][16][72];    // 9 KB  bf16 leaf tiles
    __shared__ float s_y[4][768];                   // 12 KB output staging
    // total ~38 KB -> 4 blocks/CU

    const int tid  = threadIdx.x;
    const int wv   = tid >> 6;     // wave = batch pair
    const int lane = tid & 63;
    const int n    = lane & 15;    // MFMA N index (leaf in tile)
    const int q    = lane >> 4;    // quad
    const int n3   = blockIdx.x;   // 0..63  level-3 node (y3*8+x3)
    const int bg   = blockIdx.y;   // 0..15  batch group of 8
    const int jy   = blockIdx.z;   // 0..1
    const int y3   = n3 >> 3, x3 = n3 & 7;

    const float* fdir[4] = { f_tl, f_tr, f_bl, f_br };

    // ---- per-lane head state (reused by all 8 head tiles) ----
    short8 afrag[3][2];
#pragma unroll
    for (int mt = 0; mt < 3; ++mt)
#pragma unroll
        for (int kc = 0; kc < 2; ++kc) {
            const float* src = head_w + (mt * 16 + n) * 64 + kc * 32 + q * 8;
            short8 a;
#pragma unroll
            for (int j = 0; j < 8; ++j) a[j] = (short)f2bf(src[j]);
            afrag[mt][kc] = a;
        }
    f32x4 accinit[3];
#pragma unroll
    for (int mt = 0; mt < 3; ++mt)
#pragma unroll
        for (int r = 0; r < 4; ++r) accinit[mt][r] = head_b[mt * 16 + q * 4 + r];
    // s_y scatter offsets: leaf n -> (b, dx2, c); o = mt*16 + q*4 + r
    const int lb = n >> 3, ldx = (n >> 2) & 1, lc = n & 3;
    const int lcy = lc >> 1, lcx = lc & 1;
    const int sy_base = lb * 384 + lcy * 64 + ldx * 8 + lcx * 4;
    int sy_ofs[3][4];
#pragma unroll
    for (int mt = 0; mt < 3; ++mt)
#pragma unroll
        for (int r = 0; r < 4; ++r) {
            const int o = mt * 16 + q * 4 + r;
            sy_ofs[mt][r] = sy_base + (o % 3) * 128 + (o / 12) * 16 + ((o / 3) & 3);
        }

    float (*xa)[64]  = s_xa[wv];
    float (*xb)[64]  = s_xb[wv];
    float (*lat)[16] = s_lat[wv];
    unsigned short* leaf = &s_leaf[wv][0][0];
    float* sy = s_y[wv];

    // load this wave's 2 batches
#pragma unroll
    for (int b = 0; b < 2; ++b)
        xa[b][lane] = x[(size_t)(bg * 8 + wv * 2 + b) * 64 + lane];

    // ---- path L0 -> L1 -> L2 (single child each) ----
    {
        wlat(f_in, scale, 0, xa, lat, lane);
        const int d = ((y3 >> 2) << 1) | (x3 >> 2);
        wchild(fdir[d], xa, lat, xb, lane);
    }
    {
        const int fo = 1 + ((y3 >> 2) * 2 + (x3 >> 2));
        wlat(f_in, scale, fo, xb, lat, lane);
        const int d = (((y3 >> 1) & 1) << 1) | ((x3 >> 1) & 1);
        wchild(fdir[d] + (size_t)fo * 1024, xb, lat, xa, lane);
    }
    {
        const int fo = 5 + ((y3 >> 1) * 4 + (x3 >> 1));
        wlat(f_in, scale, fo, xa, lat, lane);
        const int d = ((y3 & 1) << 1) | (x3 & 1);
        wchild(fdir[d] + (size_t)fo * 1024, xa, lat, xb, lane);
    }
    // ---- L3: children for this jy-half ----
    {
        const int fo = 21 + n3;
        wlat(f_in, scale, fo, xb, lat, lane);
#pragma unroll
        for (int jx = 0; jx < 2; ++jx)
            wchild(fdir[2 * jy + jx] + (size_t)fo * 1024, xb, lat, s_x4[wv][jx], lane);
    }

    // ---- two L4 subtrees ----
    for (int jx = 0; jx < 2; ++jx) {
        const int y4 = 2 * y3 + jy, x4c = 2 * x3 + jx;
        const int fo4 = 85 + y4 * 16 + x4c;
        wlat(f_in, scale, fo4, s_x4[wv][jx], lat, lane);
#pragma unroll
        for (int e = 0; e < 4; ++e)
            wchild(fdir[e] + (size_t)fo4 * 1024, s_x4[wv][jx], lat, s_x5[wv][e], lane);

        // ---- 4 head tiles per subtree: (p, dx2) halves ----
        for (int p = 0; p < 2; ++p) {
#pragma unroll
            for (int dx2 = 0; dx2 < 2; ++dx2) {
                const int e = 2 * p + dx2;
                const int fo5 = 341 + (2 * y4 + p) * 32 + (2 * x4c + dx2);
                wlat(f_in, scale, fo5, s_x5[wv][e], lat, lane);
#pragma unroll
                for (int c = 0; c < 4; ++c)
                    wchild_leaf(fdir[c] + (size_t)fo5 * 1024, s_x5[wv][e], lat,
                                leaf, dx2 * 4 + c, lane);
            }

            // MFMA head: 16 leaves x 48 outs, K=64
            f32x4 acc[3];
#pragma unroll
            for (int mt = 0; mt < 3; ++mt) acc[mt] = accinit[mt];
#pragma unroll
            for (int kc = 0; kc < 2; ++kc) {
                const short8 bfrag = *(const short8*)&s_leaf[wv][n][kc * 32 + q * 8];
#pragma unroll
                for (int mt = 0; mt < 3; ++mt)
                    acc[mt] = __builtin_amdgcn_mfma_f32_16x16x32_bf16(afrag[mt][kc], bfrag, acc[mt], 0, 0, 0);
            }

            // stage y: [b][ch][r2][16]
#pragma unroll
            for (int mt = 0; mt < 3; ++mt)
#pragma unroll
                for (int r = 0; r < 4; ++r) sy[sy_ofs[mt][r]] = acc[mt][r];

            // full-line stores: rows of 16 px (64 B)
            // tile base col = x5_base * 8 px  (R5 bug was *16 -> OOB stores)
            const int base_row = (4 * y3 + 2 * jy + p) * 8;
            const int base_col = (4 * x3 + 2 * jx) * 8;
#pragma unroll
            for (int s = 0; s < 3; ++s) {
                const int i  = lane + 64 * s;      // 0..191 float4 chunks
                const int c4 = i & 3;
                const int r2 = (i >> 2) & 7;
                const int bc = i >> 5;             // b*3+ch, 0..5
                const float4 v = *(const float4*)&sy[(bc * 8 + r2) * 16 + c4 * 4];
                const size_t off = ((size_t)((bg * 8 + wv * 2 + bc / 3) * 3 + (bc % 3))) * 65536
                                 + (size_t)(base_row + r2) * 256 + base_col + c4 * 4;
                *(float4*)&out[off] = v;
            }
        } // p
    } // jx
}

extern "C" void kernel_launch(void* const* d_in, const int* in_sizes, int n_in,
                              void* d_out, int out_size, void* d_ws, size_t ws_size,
                              hipStream_t stream) {
    const float* x    = (const float*)d_in[0];
    const float* f_in = (const float*)d_in[1];
    const float* f_tl = (const float*)d_in[2];
    const float* f_tr = (const float*)d_in[3];
    const float* f_bl = (const float*)d_in[4];
    const float* f_br = (const float*)d_in[5];
    const float* sc   = (const float*)d_in[6];
    const float* hw   = (const float*)d_in[7];
    const float* hb   = (const float*)d_in[8];
    float* out = (float*)d_out;

    dim3 grid(64, 16, 2);
    qtree_kernel<<<grid, NTHR, 0, stream>>>(x, f_in, f_tl, f_tr, f_bl, f_br, sc, hw, hb, out);
}